// Round 9
// baseline (108.481 us; speedup 1.0000x reference)
//
#include <hip/hip_runtime.h>
#include <math.h>
#include <utility>

namespace {

constexpr int C_  = 16;
constexpr int OR_ = 8;
constexpr int H_  = 192;
constexpr int W_  = 192;
constexpr int HW_ = H_ * W_;
constexpr int CH_ = OR_ * HW_;
constexpr float PI_F = 3.14159265358979323846f;

// LDS tile: 64x16 output tile, halo 2 each side, 4 orientation planes
// (theta-pair fusion: thetas {2b,2b+1} need planes {2b-1..2b+2}).
constexpr int TW_ = 68;               // 64 + 4, 16B-multiple rows
constexpr int TR_ = 20;               // 16 + 4
constexpr int PSZ_ = TR_ * TW_;       // 1360 floats per plane
constexpr int TSZ4_ = 4 * PSZ_;       // 5440 floats = 21.8 KB

constexpr float SQ2H = 0.70710678118654752440f;
constexpr float CT8[8] = { 1.0f,  SQ2H,  0.0f, -SQ2H, -1.0f, -SQ2H,  0.0f,  SQ2H };
constexpr float ST8[8] = { 0.0f,  SQ2H,  1.0f,  SQ2H,  0.0f, -SQ2H, -1.0f, -SQ2H };

constexpr int cfloor(float v) {
    return (v >= 0.0f) ? (int)v : (((float)(int)v == v) ? (int)v : (int)v - 1);
}

// Zero-padded corner fetch (matches reference _sample's per-corner validity).
__device__ __forceinline__ float corner(const float* __restrict__ p, int iy, int ix) {
    bool valid = ((unsigned)iy < (unsigned)H_) && ((unsigned)ix < (unsigned)W_);
    int yc = min(max(iy, 0), H_ - 1);
    int xc = min(max(ix, 0), W_ - 1);
    float v = p[yc * W_ + xc];
    return valid ? v : 0.0f;
}

// ---------------- dilation: one offset vs 5x8 register window ----------------
// Window rows = out_row-2..out_row+2, cols = X-2..X+5 (X = 4px base).
template<int TH, int HTI, int OO>
__device__ __forceinline__ void off_one(const float (&w)[5][8],
                                        const float* __restrict__ sk, float (&acc)[4]) {
    constexpr int hxi = OO % 3 - 1;
    constexpr int hyi = OO / 3 - 1;
    constexpr float ct = CT8[TH];
    constexpr float st = ST8[TH];
    constexpr float sx = ct * (float)hxi - st * (float)hyi;
    constexpr float sy = st * (float)hxi + ct * (float)hyi;
    constexpr int dx = cfloor(sx);
    constexpr int dy = cfloor(sy);
    constexpr float wx = sx - (float)dx;
    constexpr float wy = sy - (float)dy;
    constexpr int R  = dy + 2;    // 0..3
    constexpr int Cb = dx + 2;    // 0..3

    const float k = sk[(HTI + 1) * 9 + OO];   // wave-uniform LDS broadcast
    #pragma unroll
    for (int j = 0; j < 4; ++j) {
        float v;
        if constexpr (wx == 0.0f && wy == 0.0f) {
            v = w[R][Cb + j];
        } else if constexpr (wy == 0.0f) {
            const float a = w[R][Cb + j];
            v = a + wx * (w[R][Cb + j + 1] - a);
        } else if constexpr (wx == 0.0f) {
            const float a = w[R][Cb + j];
            v = a + wy * (w[R + 1][Cb + j] - a);
        } else {
            const float a0 = w[R][Cb + j];
            const float h0 = a0 + wx * (w[R][Cb + j + 1] - a0);
            const float a1 = w[R + 1][Cb + j];
            const float h1 = a1 + wx * (w[R + 1][Cb + j + 1] - a1);
            v = h0 + wy * (h1 - h0);
        }
        acc[j] = fmaxf(acc[j], v - k);
    }
}

template<int TH, int HTI, int... OOs>
__device__ __forceinline__ void off_nine(std::integer_sequence<int, OOs...>,
        const float (&w)[5][8], const float* __restrict__ sk, float (&acc)[4]) {
    (off_one<TH, HTI, OOs>(w, sk, acc), ...);
}

// Plane slot PP (absolute plane 2B-1+PP): one window feeds both thetas of the pair.
template<int B, int PP>
__device__ __forceinline__ void plane_win(const float* __restrict__ tile, int lb0,
        const float* __restrict__ sk, float (&accA)[4], float (&accB)[4]) {
    float w[5][8];
    const float* __restrict__ base = tile + PP * PSZ_ + lb0;
    #pragma unroll
    for (int r = 0; r < 5; ++r) {
        *(float4*)&w[r][0] = *(const float4*)&base[r * TW_];
        *(float4*)&w[r][4] = *(const float4*)&base[r * TW_ + 4];
    }
    using Seq9 = std::make_integer_sequence<int, 9>;
    if constexpr (PP < 3) off_nine<2 * B,     PP - 1>(Seq9{}, w, sk, accA);
    if constexpr (PP > 0) off_nine<2 * B + 1, PP - 2>(Seq9{}, w, sk, accB);
}

template<int B>
__device__ __forceinline__ void dil_pair(const float* __restrict__ tile, int lb0,
        const float* __restrict__ sk, float (&accA)[4], float (&accB)[4]) {
    plane_win<B, 0>(tile, lb0, sk, accA, accB);
    plane_win<B, 1>(tile, lb0, sk, accA, accB);
    plane_win<B, 2>(tile, lb0, sk, accA, accB);
    plane_win<B, 3>(tile, lb0, sk, accA, accB);
}

// ---------------- fused: out = dilation(convection(u)), theta-pair per block ----
// One block per (c, theta-pair b, xtile, ytile): stage conv output for planes
// 2b-1..2b+2 into LDS (computed on the fly from u), then register-window
// dilation for thetas 2b and 2b+1. 2304 blocks.
__global__ __launch_bounds__(256) void fused_kernel(
        const float* __restrict__ u, const float* __restrict__ g0,
        const float* __restrict__ mp, float* __restrict__ out) {
    __shared__ __align__(16) float tile[TSZ4_];
    __shared__ float s_k[27];

    const int z = blockIdx.z;
    const int c = z >> 2;
    const int b = z & 3;
    const int thA = 2 * b;
    const int t = threadIdx.x;

    // ---- kernel-cost table (c-dependent only) ----
    if (t < 27) {
        const int hti = t / 9 - 1;
        const int hyi = (t / 3) % 3 - 1;
        const int hxi = t % 3 - 1;
        const float hx = (float)hxi, hy = (float)hyi;
        const float hth  = (float)hti * (2.0f * PI_F / OR_);
        const float half = 0.5f * hth;
        float q;
        if (fabsf(half) < 1e-4f) q = 1.0f - half * half * (1.0f / 3.0f);
        else                     q = half / tanf(half);
        const float c1 = q * hx + half * hy;
        const float c2 = -half * hx + q * hy;
        const float c3 = hth;
        const float m0 = mp[c * 3 + 0], m1 = mp[c * 3 + 1], m2 = mp[c * 3 + 2];
        const float d2 = (m0 * c1) * (m0 * c1) + (m1 * c2) * (m1 * c2) + (m2 * c3) * (m2 * c3);
        const float ee = 2.0f * 0.65f / (2.0f * 0.65f - 1.0f);
        const float nu = (2.0f * 0.65f - 1.0f) * powf(2.0f * 0.65f, -ee);
        s_k[t] = nu * powf(d2, 0.5f * ee);
    }

    // ---- conv params + staging (all 256 threads) ----
    const float gx0  = g0[c * 3 + 0];
    const float gy0  = g0[c * 3 + 1];
    const float gth0 = g0[c * 3 + 2];

    float sg, cg;
    sincosf(gth0, &sg, &cg);

    float tc0 = -gth0 * (OR_ / (2.0f * PI_F));
    tc0 = tc0 - floorf(tc0 * (1.0f / OR_)) * (float)OR_;
    const float t0f = floorf(tc0);
    const float wt = tc0 - t0f;
    const int tbase = ((int)t0f) & 7;

    const int bx0 = blockIdx.x * 64 - 2;
    const int by0 = blockIdx.y * 16 - 2;
    const float* __restrict__ cbase = u + c * CH_;

    #pragma unroll
    for (int pp = 0; pp < 4; ++pp) {
        const int plane = (thA + pp - 1 + OR_) & 7;
        const float ca = CT8[plane] * cg + ST8[plane] * sg;   // cos(plane*pi/4 - gth0)
        const float sa = ST8[plane] * cg - CT8[plane] * sg;   // sin(plane*pi/4 - gth0)
        const float dxs = ca * gx0 - sa * gy0;
        const float dys = sa * gx0 + ca * gy0;
        const float mx = -dxs, my = -dys;
        const float fxi = floorf(mx), fyi = floorf(my);
        const float wxp = mx - fxi, wyp = my - fyi;
        const int sxo = (int)fxi, syo = (int)fyi;
        const int t0i = (tbase + plane) & 7;
        const int t1i = (tbase + plane + 1) & 7;
        const float* __restrict__ p0 = cbase + t0i * HW_;
        const float* __restrict__ p1 = cbase + t1i * HW_;
        const float w00 = (1.f - wyp) * (1.f - wxp);
        const float w01 = (1.f - wyp) * wxp;
        const float w10 = wyp * (1.f - wxp);
        const float w11 = wyp * wxp;

        for (int i = t; i < PSZ_; i += 256) {
            const int rr  = i / TW_;
            const int col = i - rr * TW_;
            const int gy = by0 + rr;
            const int gx = bx0 + col;
            float v = 0.0f;
            if ((unsigned)gy < (unsigned)H_ && (unsigned)gx < (unsigned)W_) {
                const int ix0 = gx + sxo;
                const int iy0 = gy + syo;
                float v0, v1;
                if (ix0 >= 0 && ix0 + 1 < W_ && iy0 >= 0 && iy0 + 1 < H_) {
                    const int o = iy0 * W_ + ix0;
                    const float a00 = p0[o],      a01 = p0[o + 1];
                    const float a10 = p0[o + W_], a11 = p0[o + W_ + 1];
                    const float b00 = p1[o],      b01 = p1[o + 1];
                    const float b10 = p1[o + W_], b11 = p1[o + W_ + 1];
                    const float ha0 = a00 + wxp * (a01 - a00);
                    const float ha1 = a10 + wxp * (a11 - a10);
                    const float hb0 = b00 + wxp * (b01 - b00);
                    const float hb1 = b10 + wxp * (b11 - b10);
                    v0 = ha0 + wyp * (ha1 - ha0);
                    v1 = hb0 + wyp * (hb1 - hb0);
                } else {
                    v0 = w00 * corner(p0, iy0, ix0)     + w01 * corner(p0, iy0, ix0 + 1)
                       + w10 * corner(p0, iy0 + 1, ix0) + w11 * corner(p0, iy0 + 1, ix0 + 1);
                    v1 = w00 * corner(p1, iy0, ix0)     + w01 * corner(p1, iy0, ix0 + 1)
                       + w10 * corner(p1, iy0 + 1, ix0) + w11 * corner(p1, iy0 + 1, ix0 + 1);
                }
                v = v0 + wt * (v1 - v0);
            }
            tile[pp * PSZ_ + i] = v;
        }
    }
    __syncthreads();

    // ---- dilation: 4 adjacent x px per thread, one row, both thetas ----
    const int xg = t & 15;
    const int y  = t >> 4;
    const int lb0 = y * TW_ + xg * 4;

    float accA[4], accB[4];
    #pragma unroll
    for (int j = 0; j < 4; ++j) { accA[j] = -INFINITY; accB[j] = -INFINITY; }

    switch (b) {
        case 0: dil_pair<0>(tile, lb0, s_k, accA, accB); break;
        case 1: dil_pair<1>(tile, lb0, s_k, accA, accB); break;
        case 2: dil_pair<2>(tile, lb0, s_k, accA, accB); break;
        case 3: dil_pair<3>(tile, lb0, s_k, accA, accB); break;
        default: __builtin_unreachable();
    }

    const int gx = blockIdx.x * 64 + xg * 4;
    const int gy = blockIdx.y * 16 + y;
    float* __restrict__ op = out + c * CH_ + gy * W_ + gx;
    float4 rA, rB;
    rA.x = accA[0]; rA.y = accA[1]; rA.z = accA[2]; rA.w = accA[3];
    rB.x = accB[0]; rB.y = accB[1]; rB.z = accB[2]; rB.w = accB[3];
    *(float4*)&op[(thA)     * HW_] = rA;
    *(float4*)&op[(thA + 1) * HW_] = rB;
}

} // anonymous namespace

extern "C" void kernel_launch(void* const* d_in, const int* in_sizes, int n_in,
                              void* d_out, int out_size, void* d_ws, size_t ws_size,
                              hipStream_t stream) {
    const float* u   = (const float*)d_in[0];
    const float* g0  = (const float*)d_in[1];
    const float* mpp = (const float*)d_in[2];
    float* out = (float*)d_out;
    float* ws  = (float*)d_ws;

    dim3 grid(W_ / 64, H_ / 16, C_ * 4);   // x-tiles, y-tiles, c * theta-pairs
    dim3 block(256);

    // iteration 1: ws = dil(conv(u));  iteration 2: out = dil(conv(ws))
    fused_kernel<<<grid, block, 0, stream>>>(u,  g0, mpp, ws);
    fused_kernel<<<grid, block, 0, stream>>>(ws, g0, mpp, out);
}

// Round 10
// 70.508 us; speedup vs baseline: 1.5386x; 1.5386x over previous
//
#include <hip/hip_runtime.h>
#include <math.h>
#include <utility>

namespace {

constexpr int C_  = 16;
constexpr int OR_ = 8;
constexpr int H_  = 192;
constexpr int W_  = 192;
constexpr int HW_ = H_ * W_;
constexpr int CH_ = OR_ * HW_;
constexpr float PI_F = 3.14159265358979323846f;

// Padded conv-output workspace: image px (y,x) -> padded (y+2, x+2).
// PW_ multiple of 4 -> every window base (col = gx, gx % 4 == 0) is 16B aligned.
constexpr int PH_  = 196;             // 192 + 2 top + 2 bottom
constexpr int PW_  = 208;             // 192 + 2 left + 14 right (alignment slack)
constexpr int PPL_ = PH_ * PW_;       // 40768 floats per plane
constexpr int NPL_ = C_ * OR_;        // 128 planes
constexpr int PAD_CELLS_PER_PLANE = 2 * PW_ + 2 * PW_ + (H_ * 16); // top,bottom rows + side cols

constexpr float SQ2H = 0.70710678118654752440f;
constexpr float CT8[8] = { 1.0f,  SQ2H,  0.0f, -SQ2H, -1.0f, -SQ2H,  0.0f,  SQ2H };
constexpr float ST8[8] = { 0.0f,  SQ2H,  1.0f,  SQ2H,  0.0f, -SQ2H, -1.0f, -SQ2H };

constexpr int cfloor(float v) {
    return (v >= 0.0f) ? (int)v : (((float)(int)v == v) ? (int)v : (int)v - 1);
}

// Zero-padded corner fetch (matches reference _sample's per-corner validity).
__device__ __forceinline__ float corner(const float* __restrict__ p, int iy, int ix) {
    bool valid = ((unsigned)iy < (unsigned)H_) && ((unsigned)ix < (unsigned)W_);
    int yc = min(max(iy, 0), H_ - 1);
    int xc = min(max(ix, 0), W_ - 1);
    float v = p[yc * W_ + xc];
    return valid ? v : 0.0f;
}

// ---------------- zero the pad borders of wsA (idempotent, once per launch) ----
__global__ __launch_bounds__(256) void zeropad_kernel(float* __restrict__ wsA) {
    const int idx = blockIdx.x * 256 + threadIdx.x;
    const int total = NPL_ * PAD_CELLS_PER_PLANE;
    if (idx >= total) return;
    const int plane = idx / PAD_CELLS_PER_PLANE;
    int i = idx - plane * PAD_CELLS_PER_PLANE;
    int r, col;
    if (i < 2 * PW_) {                        // top rows 0,1
        r = i / PW_;  col = i % PW_;
    } else if (i < 4 * PW_) {                 // bottom rows 194,195
        i -= 2 * PW_; r = 194 + i / PW_; col = i % PW_;
    } else {                                  // side cols: 0,1 and 194..207
        i -= 4 * PW_;
        r = 2 + i / 16;
        const int cs = i % 16;
        col = (cs < 2) ? cs : (192 + cs);     // cs=2 -> 194 ... cs=15 -> 207
    }
    wsA[plane * PPL_ + r * PW_ + col] = 0.0f;
}

// ---------------- convection_m2 (round-7 kernel, writes PADDED layout) --------
__global__ __launch_bounds__(256) void conv_kernel(
        const float* __restrict__ u, const float* __restrict__ g0,
        float* __restrict__ wsA) {
    const int tx  = threadIdx.x & 63;
    const int ty0 = (threadIdx.x >> 6) * 4;
    const int x   = blockIdx.x * 64 + tx;
    const int y0  = blockIdx.y * 16 + ty0;
    const int z = blockIdx.z;
    const int c  = z >> 3;
    const int th = z & 7;

    const float gx0  = g0[c * 3 + 0];
    const float gy0  = g0[c * 3 + 1];
    const float gth0 = g0[c * 3 + 2];

    const float a = (float)th * (2.0f * PI_F / OR_) - gth0;
    float sa, ca;
    sincosf(a, &sa, &ca);
    const float dxs = ca * gx0 - sa * gy0;
    const float dys = sa * gx0 + ca * gy0;

    const float fx = (float)x - dxs;
    const float fy = (float)y0 - dys;
    const float fx0 = floorf(fx), fy0 = floorf(fy);
    const float wx = fx - fx0, wy = fy - fy0;
    const int ix0 = (int)fx0, iy0 = (int)fy0;

    float tc = (float)th - gth0 * (OR_ / (2.0f * PI_F));
    tc = tc - floorf(tc * (1.0f / OR_)) * (float)OR_;
    const float t0f = floorf(tc);
    const float wt = tc - t0f;
    const int t0i = ((int)t0f) & 7;
    const int t1i = (t0i + 1) & 7;

    const float* __restrict__ p0 = u + c * CH_ + t0i * HW_;
    const float* __restrict__ p1 = u + c * CH_ + t1i * HW_;

    float r0, r1, r2, r3;
    if (ix0 >= 0 && ix0 + 1 < W_ && iy0 >= 0 && iy0 + 4 < H_) {
        const int o = iy0 * W_ + ix0;
        float a00 = p0[o],          a01 = p0[o + 1];
        float a10 = p0[o + W_],     a11 = p0[o + W_ + 1];
        float a20 = p0[o + 2 * W_], a21 = p0[o + 2 * W_ + 1];
        float a30 = p0[o + 3 * W_], a31 = p0[o + 3 * W_ + 1];
        float a40 = p0[o + 4 * W_], a41 = p0[o + 4 * W_ + 1];
        float b00 = p1[o],          b01 = p1[o + 1];
        float b10 = p1[o + W_],     b11 = p1[o + W_ + 1];
        float b20 = p1[o + 2 * W_], b21 = p1[o + 2 * W_ + 1];
        float b30 = p1[o + 3 * W_], b31 = p1[o + 3 * W_ + 1];
        float b40 = p1[o + 4 * W_], b41 = p1[o + 4 * W_ + 1];
        float ha0 = a00 + wx * (a01 - a00);
        float ha1 = a10 + wx * (a11 - a10);
        float ha2 = a20 + wx * (a21 - a20);
        float ha3 = a30 + wx * (a31 - a30);
        float ha4 = a40 + wx * (a41 - a40);
        float hb0 = b00 + wx * (b01 - b00);
        float hb1 = b10 + wx * (b11 - b10);
        float hb2 = b20 + wx * (b21 - b20);
        float hb3 = b30 + wx * (b31 - b30);
        float hb4 = b40 + wx * (b41 - b40);
        float va0 = ha0 + wy * (ha1 - ha0);
        float va1 = ha1 + wy * (ha2 - ha1);
        float va2 = ha2 + wy * (ha3 - ha2);
        float va3 = ha3 + wy * (ha4 - ha3);
        float vb0 = hb0 + wy * (hb1 - hb0);
        float vb1 = hb1 + wy * (hb2 - hb1);
        float vb2 = hb2 + wy * (hb3 - hb2);
        float vb3 = hb3 + wy * (hb4 - hb3);
        r0 = va0 + wt * (vb0 - va0);
        r1 = va1 + wt * (vb1 - va1);
        r2 = va2 + wt * (vb2 - va2);
        r3 = va3 + wt * (vb3 - va3);
    } else {
        const float w00 = (1.f - wy) * (1.f - wx);
        const float w01 = (1.f - wy) * wx;
        const float w10 = wy * (1.f - wx);
        const float w11 = wy * wx;
        float rr[4];
        #pragma unroll
        for (int j = 0; j < 4; ++j) {
            const int iy = iy0 + j;
            float v0 = w00 * corner(p0, iy, ix0)     + w01 * corner(p0, iy, ix0 + 1)
                     + w10 * corner(p0, iy + 1, ix0) + w11 * corner(p0, iy + 1, ix0 + 1);
            float v1 = w00 * corner(p1, iy, ix0)     + w01 * corner(p1, iy, ix0 + 1)
                     + w10 * corner(p1, iy + 1, ix0) + w11 * corner(p1, iy + 1, ix0 + 1);
            rr[j] = v0 + wt * (v1 - v0);
        }
        r0 = rr[0]; r1 = rr[1]; r2 = rr[2]; r3 = rr[3];
    }
    float* __restrict__ op = wsA + (c * OR_ + th) * PPL_ + (y0 + 2) * PW_ + (x + 2);
    op[0]       = r0;
    op[PW_]     = r1;
    op[2 * PW_] = r2;
    op[3 * PW_] = r3;
}

// ---------------- dilation: direct-from-padded-global register windows --------
// Window w[5][8]: padded rows gy..gy+4 (image gy-2..gy+2), cols gx..gx+7
// (image gx-2..gx+5). Same constexpr geometry as round 7.
template<int TH, int PP, int OO>
__device__ __forceinline__ void off_one(const float (&w)[5][8],
                                        const float* __restrict__ sk, float (&acc)[4]) {
    constexpr int hxi = OO % 3 - 1;
    constexpr int hyi = OO / 3 - 1;
    constexpr float ct = CT8[TH];
    constexpr float st = ST8[TH];
    constexpr float sx = ct * (float)hxi - st * (float)hyi;
    constexpr float sy = st * (float)hxi + ct * (float)hyi;
    constexpr int dx = cfloor(sx);
    constexpr int dy = cfloor(sy);
    constexpr float wx = sx - (float)dx;
    constexpr float wy = sy - (float)dy;
    constexpr int R  = dy + 2;    // 0..3
    constexpr int Cb = dx + 2;    // 0..3

    const float k = sk[PP * 9 + OO];   // wave-uniform LDS broadcast
    #pragma unroll
    for (int j = 0; j < 4; ++j) {
        float v;
        if constexpr (wx == 0.0f && wy == 0.0f) {
            v = w[R][Cb + j];
        } else if constexpr (wy == 0.0f) {
            const float a = w[R][Cb + j];
            v = a + wx * (w[R][Cb + j + 1] - a);
        } else if constexpr (wx == 0.0f) {
            const float a = w[R][Cb + j];
            v = a + wy * (w[R + 1][Cb + j] - a);
        } else {
            const float a0 = w[R][Cb + j];
            const float h0 = a0 + wx * (w[R][Cb + j + 1] - a0);
            const float a1 = w[R + 1][Cb + j];
            const float h1 = a1 + wx * (w[R + 1][Cb + j + 1] - a1);
            v = h0 + wy * (h1 - h0);
        }
        acc[j] = fmaxf(acc[j], v - k);
    }
}

template<int TH, int PP, int... OOs>
__device__ __forceinline__ void off_nine(std::integer_sequence<int, OOs...>,
        const float (&w)[5][8], const float* __restrict__ sk, float (&acc)[4]) {
    (off_one<TH, PP, OOs>(w, sk, acc), ...);
}

// Plane slot PP (hti = PP-1): 10 aligned dwordx4 global loads from padded plane.
template<int TH, int PP>
__device__ __forceinline__ void do_plane(const float* __restrict__ winbase,
                                         const float* __restrict__ sk, float (&acc)[4]) {
    constexpr int plane = (TH + PP - 1 + OR_) & 7;
    float w[5][8];
    const float* __restrict__ base = winbase + plane * PPL_;
    #pragma unroll
    for (int r = 0; r < 5; ++r) {
        *(float4*)&w[r][0] = *(const float4*)&base[r * PW_];
        *(float4*)&w[r][4] = *(const float4*)&base[r * PW_ + 4];
    }
    off_nine<TH, PP>(std::make_integer_sequence<int, 9>{}, w, sk, acc);
}

template<int TH>
__device__ __forceinline__ void dil_theta(const float* __restrict__ winbase,
        const float* __restrict__ sk, float (&acc)[4]) {
    do_plane<TH, 0>(winbase, sk, acc);
    do_plane<TH, 1>(winbase, sk, acc);
    do_plane<TH, 2>(winbase, sk, acc);
}

// One block per (c,theta): no LDS staging — windows read straight from the
// padded ws (L1-resident per block). 4608 blocks, 256 threads.
__global__ __launch_bounds__(256) void dil_kernel(
        const float* __restrict__ wsA, const float* __restrict__ mp,
        float* __restrict__ out) {
    __shared__ float s_k[27];

    const int z = blockIdx.z;
    const int c  = z >> 3;
    const int th = z & 7;
    const int t = threadIdx.x;

    if (t < 27) {
        const int hti = t / 9 - 1;
        const int hyi = (t / 3) % 3 - 1;
        const int hxi = t % 3 - 1;
        const float hx = (float)hxi, hy = (float)hyi;
        const float hth  = (float)hti * (2.0f * PI_F / OR_);
        const float half = 0.5f * hth;
        float q;
        if (fabsf(half) < 1e-4f) q = 1.0f - half * half * (1.0f / 3.0f);
        else                     q = half / tanf(half);
        const float c1 = q * hx + half * hy;
        const float c2 = -half * hx + q * hy;
        const float c3 = hth;
        const float m0 = mp[c * 3 + 0], m1 = mp[c * 3 + 1], m2 = mp[c * 3 + 2];
        const float d2 = (m0 * c1) * (m0 * c1) + (m1 * c2) * (m1 * c2) + (m2 * c3) * (m2 * c3);
        const float ee = 2.0f * 0.65f / (2.0f * 0.65f - 1.0f);
        const float nu = (2.0f * 0.65f - 1.0f) * powf(2.0f * 0.65f, -ee);
        s_k[t] = nu * powf(d2, 0.5f * ee);
    }
    __syncthreads();

    const int xg = t & 15;                       // 4 px: X..X+3, X = xg*4
    const int y  = t >> 4;                       // row 0..15
    const int gx = blockIdx.x * 64 + xg * 4;
    const int gy = blockIdx.y * 16 + y;

    // window base: padded (gy, gx) == image (gy-2, gx-2); gx % 4 == 0 -> aligned
    const float* __restrict__ winbase = wsA + c * OR_ * PPL_ + gy * PW_ + gx;

    float acc[4];
    #pragma unroll
    for (int j = 0; j < 4; ++j) acc[j] = -INFINITY;

    switch (th) {
        case 0: dil_theta<0>(winbase, s_k, acc); break;
        case 1: dil_theta<1>(winbase, s_k, acc); break;
        case 2: dil_theta<2>(winbase, s_k, acc); break;
        case 3: dil_theta<3>(winbase, s_k, acc); break;
        case 4: dil_theta<4>(winbase, s_k, acc); break;
        case 5: dil_theta<5>(winbase, s_k, acc); break;
        case 6: dil_theta<6>(winbase, s_k, acc); break;
        case 7: dil_theta<7>(winbase, s_k, acc); break;
        default: __builtin_unreachable();
    }

    float4 r;
    r.x = acc[0]; r.y = acc[1]; r.z = acc[2]; r.w = acc[3];
    *(float4*)&out[c * CH_ + th * HW_ + gy * W_ + gx] = r;
}

} // anonymous namespace

extern "C" void kernel_launch(void* const* d_in, const int* in_sizes, int n_in,
                              void* d_out, int out_size, void* d_ws, size_t ws_size,
                              hipStream_t stream) {
    const float* u   = (const float*)d_in[0];
    const float* g0  = (const float*)d_in[1];
    const float* mpp = (const float*)d_in[2];
    float* out = (float*)d_out;
    float* wsA = (float*)d_ws;                       // padded conv output, 20.9 MB
    float* wsB = wsA + NPL_ * PPL_;                  // unpadded dil-1 output, 18.9 MB

    dim3 grid(W_ / 64, H_ / 16, C_ * OR_);
    dim3 block(256);

    const int pad_total = NPL_ * PAD_CELLS_PER_PLANE;
    zeropad_kernel<<<(pad_total + 255) / 256, 256, 0, stream>>>(wsA);

    // iter 1
    conv_kernel<<<grid, block, 0, stream>>>(u,   g0,  wsA);
    dil_kernel <<<grid, block, 0, stream>>>(wsA, mpp, wsB);
    // iter 2
    conv_kernel<<<grid, block, 0, stream>>>(wsB, g0,  wsA);
    dil_kernel <<<grid, block, 0, stream>>>(wsA, mpp, out);
}